// Round 3
// baseline (279.834 us; speedup 1.0000x reference)
//
#include <hip/hip_runtime.h>

namespace {
constexpr int NB = 32;      // batch
constexpr int NN = 2000;    // nodes
constexpr int NE = 64000;   // edges
constexpr int ND = 128;     // feature dim
constexpr int NCHUNK = 63;  // ceil(2000/32) node tiles per batch
constexpr int NXCD = 8;
constexpr int BPX = NB / NXCD;  // batches per XCD = 4

// ---- workspace layout (bytes); every region fully written before read ----
constexpr size_t OFF_DINV = 0;                               // float[2048]
constexpr size_t OFF_WSUM = OFF_DINV + 2048 * 4;             // float[2048]
constexpr size_t OFF_OFFS = OFF_WSUM + 2048 * 4;             // int[2052]
constexpr size_t OFF_Y    = OFF_OFFS + 2052 * 4;             // float[NB*ND]
constexpr size_t OFF_CSR  = OFF_Y + (size_t)NB * ND * 4;     // int2[NE]
} // namespace

// ---- one-shot setup: histogram, dinv/wsum, scan, CSR fill, y zero ----
__global__ __launch_bounds__(1024) void k_setup(const int* __restrict__ src,
                                                const int* __restrict__ dst,
                                                float* __restrict__ dinv_g,
                                                float* __restrict__ wsum_g,
                                                int* __restrict__ offs_g,
                                                int2* __restrict__ csr,
                                                float* __restrict__ y) {
    __shared__ int   s_cnt[2048];
    __shared__ float s_dinv[2048];
    __shared__ float s_wsum[2048];
    __shared__ int   s_cur[2048];
    const int t = threadIdx.x;
    s_cnt[t] = 0; s_cnt[t + 1024] = 0;
    __syncthreads();

    // in-degree histogram (LDS atomics), int4 loads
    const int4* dst4 = (const int4*)dst;
    for (int e = t; e < NE / 4; e += 1024) {
        int4 d = dst4[e];
        atomicAdd(&s_cnt[d.x], 1); atomicAdd(&s_cnt[d.y], 1);
        atomicAdd(&s_cnt[d.z], 1); atomicAdd(&s_cnt[d.w], 1);
    }
    __syncthreads();

    // dinv, wsum self-loop term, cursor init
    for (int n = t; n < 2048; n += 1024) {
        float di = rsqrtf((float)(s_cnt[n] + 1));   // deg = in_degree + 1
        s_dinv[n] = di;
        s_wsum[n] = di * di;
        s_cur[n] = 0;
        if (n < NN) dinv_g[n] = di;
    }
    for (int i = t; i < NB * ND; i += 1024) y[i] = 0.f;
    __syncthreads();

    // Hillis-Steele inclusive scan of s_cnt
    for (int off = 1; off < 2048; off <<= 1) {
        int v0 = (t >= off) ? s_cnt[t - off] : 0;
        int v1 = (t + 1024 >= off) ? s_cnt[t + 1024 - off] : 0;
        __syncthreads();
        s_cnt[t] += v0;
        s_cnt[t + 1024] += v1;
        __syncthreads();
    }

    // CSR fill: exclusive base = (d==0) ? 0 : s_cnt[d-1]; cursor in LDS
    const int4* src4 = (const int4*)src;
    for (int e = t; e < NE / 4; e += 1024) {
        int4 s4 = src4[e];
        int4 d4 = dst4[e];
        int ss[4] = {s4.x, s4.y, s4.z, s4.w};
        int dd[4] = {d4.x, d4.y, d4.z, d4.w};
        #pragma unroll
        for (int q = 0; q < 4; q++) {
            float w = s_dinv[ss[q]] * s_dinv[dd[q]];
            atomicAdd(&s_wsum[ss[q]], w);           // out-edge term of wsum
            int base = dd[q] ? s_cnt[dd[q] - 1] : 0;
            int p = base + atomicAdd(&s_cur[dd[q]], 1);
            csr[p] = make_int2(ss[q], __float_as_int(w));
        }
    }
    __syncthreads();

    for (int n = t; n < NN; n += 1024) wsum_g[n] = s_wsum[n];
    if (t == 0) offs_g[0] = 0;
    offs_g[t + 1]    = s_cnt[t];          // exclusive offsets; indices <= 2048
    offs_g[t + 1025] = s_cnt[t + 1024];
}

// ---- fused: gather 32-node tile -> LDS (row-major), GEMM vs W1, relu,
//      wsum-weighted node reduction into y ----
__global__ __launch_bounds__(128) void k_fused(const float* __restrict__ X,
                                               const int* __restrict__ offs,
                                               const int2* __restrict__ csr,
                                               const float* __restrict__ dinv,
                                               const float* __restrict__ W1,
                                               const float* __restrict__ b1,
                                               const float* __restrict__ wsum,
                                               float* __restrict__ y) {
    __shared__ float4 As4[32 * 33];   // As4[row*33 + kquad]; stride 33 breaks bank alias
    __shared__ float  yred[128];
    const int tid = threadIdx.x;

    // XCD batch-partition swizzle: each XCD's L2 only sees 4 batches (~4 MB X)
    const int L     = blockIdx.x;
    const int xcd   = L & (NXCD - 1);
    const int slot  = L >> 3;
    const int b     = xcd * BPX + slot / NCHUNK;
    const int chunk = slot % NCHUNK;
    const int n0    = chunk * 32;

    const float4* __restrict__ Xb4 = (const float4*)(X + (size_t)b * NN * ND); // row stride 32

    // ---- gather: group g (32 lanes) owns rows g*8..g*8+7; lane c owns feature quad c ----
    const int g = tid >> 5, c = tid & 31;
    #pragma unroll 2
    for (int i = 0; i < 8; i++) {
        const int j = g * 8 + i;
        const int n = n0 + j;
        float4 a = make_float4(0.f, 0.f, 0.f, 0.f);
        if (n < NN) {
            float sn = dinv[n]; sn *= sn;
            float4 x = Xb4[n * 32 + c];
            a.x = sn * x.x; a.y = sn * x.y; a.z = sn * x.z; a.w = sn * x.w;
            int e0 = offs[n], e1 = offs[n + 1];
            #pragma unroll 4
            for (int e = e0; e < e1; e++) {
                int2 ed = csr[e];
                float w = __int_as_float(ed.y);
                float4 xs = Xb4[ed.x * 32 + c];
                a.x = fmaf(w, xs.x, a.x);
                a.y = fmaf(w, xs.y, a.y);
                a.z = fmaf(w, xs.z, a.z);
                a.w = fmaf(w, xs.w, a.w);
            }
        }
        As4[j * 33 + c] = a;
    }
    yred[tid] = 0.f;
    __syncthreads();

    // ---- GEMM: thread (cg=c, rg=g) computes rows g*8..+7 x cols 4c..4c+3 ----
    float4 acc[8];
    #pragma unroll
    for (int i = 0; i < 8; i++) acc[i] = make_float4(0.f, 0.f, 0.f, 0.f);
    const float4* __restrict__ W4 = (const float4*)W1 + c;   // W4[k*32]
    #pragma unroll 2
    for (int k4 = 0; k4 < 32; k4++) {
        float4 w0 = W4[(4 * k4 + 0) * 32];
        float4 w1 = W4[(4 * k4 + 1) * 32];
        float4 w2 = W4[(4 * k4 + 2) * 32];
        float4 w3 = W4[(4 * k4 + 3) * 32];
        #pragma unroll
        for (int i = 0; i < 8; i++) {
            float4 a = As4[(g * 8 + i) * 33 + k4];
            acc[i].x = fmaf(a.x, w0.x, acc[i].x);
            acc[i].x = fmaf(a.y, w1.x, acc[i].x);
            acc[i].x = fmaf(a.z, w2.x, acc[i].x);
            acc[i].x = fmaf(a.w, w3.x, acc[i].x);
            acc[i].y = fmaf(a.x, w0.y, acc[i].y);
            acc[i].y = fmaf(a.y, w1.y, acc[i].y);
            acc[i].y = fmaf(a.z, w2.y, acc[i].y);
            acc[i].y = fmaf(a.w, w3.y, acc[i].y);
            acc[i].z = fmaf(a.x, w0.z, acc[i].z);
            acc[i].z = fmaf(a.y, w1.z, acc[i].z);
            acc[i].z = fmaf(a.z, w2.z, acc[i].z);
            acc[i].z = fmaf(a.w, w3.z, acc[i].z);
            acc[i].w = fmaf(a.x, w0.w, acc[i].w);
            acc[i].w = fmaf(a.y, w1.w, acc[i].w);
            acc[i].w = fmaf(a.z, w2.w, acc[i].w);
            acc[i].w = fmaf(a.w, w3.w, acc[i].w);
        }
    }

    // ---- epilogue: relu + wsum-weighted reduce over this group's 8 rows ----
    float4 bias = ((const float4*)b1)[c];
    float4 ya = make_float4(0.f, 0.f, 0.f, 0.f);
    #pragma unroll
    for (int i = 0; i < 8; i++) {
        int n = n0 + g * 8 + i;
        if (n < NN) {
            float wn = wsum[n];
            ya.x = fmaf(wn, fmaxf(acc[i].x + bias.x, 0.f), ya.x);
            ya.y = fmaf(wn, fmaxf(acc[i].y + bias.y, 0.f), ya.y);
            ya.z = fmaf(wn, fmaxf(acc[i].z + bias.z, 0.f), ya.z);
            ya.w = fmaf(wn, fmaxf(acc[i].w + bias.w, 0.f), ya.w);
        }
    }
    atomicAdd(&yred[4 * c + 0], ya.x);
    atomicAdd(&yred[4 * c + 1], ya.y);
    atomicAdd(&yred[4 * c + 2], ya.z);
    atomicAdd(&yred[4 * c + 3], ya.w);
    __syncthreads();
    atomicAdd(&y[b * ND + tid], yred[tid]);
}

// ---- out[b,:] = (1/N) * y[b,:] @ W2 + b2 ----
__global__ __launch_bounds__(128) void k_out(const float* __restrict__ y,
                                             const float* __restrict__ W2,
                                             const float* __restrict__ b2,
                                             float* __restrict__ out) {
    __shared__ float ys[128];
    const int b = blockIdx.x;
    const int d = threadIdx.x;
    ys[d] = y[b * ND + d] * (1.f / (float)NN);
    __syncthreads();
    float acc = b2[d];
    #pragma unroll 8
    for (int k = 0; k < 128; k++)
        acc = fmaf(ys[k], W2[k * ND + d], acc);
    out[b * ND + d] = acc;
}

extern "C" void kernel_launch(void* const* d_in, const int* in_sizes, int n_in,
                              void* d_out, int out_size, void* d_ws, size_t ws_size,
                              hipStream_t stream) {
    (void)in_sizes; (void)n_in; (void)out_size; (void)ws_size;
    const float* X   = (const float*)d_in[0];   // gene_emb [B,N,128] fp32
    const int*   src = (const int*)d_in[1];     // edge_src [E]
    const int*   dst = (const int*)d_in[2];     // edge_dst [E]
    const float* W1  = (const float*)d_in[3];
    const float* b1  = (const float*)d_in[4];
    const float* W2  = (const float*)d_in[5];
    const float* b2  = (const float*)d_in[6];
    float* out = (float*)d_out;

    char* ws = (char*)d_ws;
    float* dinv = (float*)(ws + OFF_DINV);
    float* wsum = (float*)(ws + OFF_WSUM);
    int*   offs = (int*)  (ws + OFF_OFFS);
    float* y    = (float*)(ws + OFF_Y);
    int2*  csr  = (int2*) (ws + OFF_CSR);

    k_setup<<<1, 1024, 0, stream>>>(src, dst, dinv, wsum, offs, csr, y);
    k_fused<<<NXCD * BPX * NCHUNK, 128, 0, stream>>>(X, offs, csr, dinv, W1, b1, wsum, y);
    k_out<<<NB, 128, 0, stream>>>(y, W2, b2, out);
}

// Round 4
// 245.922 us; speedup vs baseline: 1.1379x; 1.1379x over previous
//
#include <hip/hip_runtime.h>

namespace {
constexpr int NB = 32;      // batch
constexpr int NN = 2000;    // nodes
constexpr int NE = 64000;   // edges
constexpr int ND = 128;     // feature dim
constexpr int NCHUNK = 63;  // ceil(2000/32) node tiles per batch
constexpr int NXCD = 8;
constexpr int BPX = NB / NXCD;  // batches per XCD = 4

// ---- workspace layout (bytes) ----
constexpr size_t OFF_CNT  = 0;                           // int[2048]  (memset 0)
constexpr size_t OFF_CUR  = OFF_CNT  + 2048 * 4;         // int[2048]  (memset 0)
constexpr size_t OFF_DINV = OFF_CUR  + 2048 * 4;         // float[2048]
constexpr size_t OFF_WSUM = OFF_DINV + 2048 * 4;         // float[2048]
constexpr size_t OFF_OFFS = OFF_WSUM + 2048 * 4;         // int[2052]
constexpr size_t OFF_Y    = OFF_OFFS + 2052 * 4;         // float[NB*ND]
constexpr size_t OFF_CSR  = OFF_Y    + (size_t)NB * ND * 4;  // int2[NE]
constexpr size_t MEMSET_BYTES = 2048 * 4 * 2;            // cnt + cur only
} // namespace

// ---- S1: in-degree histogram, edge-parallel, global atomics ----
__global__ void k_hist(const int* __restrict__ dst, int* __restrict__ cnt) {
    int e = blockIdx.x * 256 + threadIdx.x;
    if (e < NE / 4) {
        int4 d = ((const int4*)dst)[e];
        atomicAdd(&cnt[d.x], 1); atomicAdd(&cnt[d.y], 1);
        atomicAdd(&cnt[d.z], 1); atomicAdd(&cnt[d.w], 1);
    }
}

// ---- S2: dinv/wsum-init, exclusive scan -> offs, y zero (single small block) ----
__global__ __launch_bounds__(1024) void k_scan(const int* __restrict__ cnt,
                                               float* __restrict__ dinv_g,
                                               float* __restrict__ wsum_g,
                                               int* __restrict__ offs_g,
                                               float* __restrict__ y) {
    __shared__ int s[2048];
    const int t = threadIdx.x;
    int c0 = cnt[t], c1 = cnt[t + 1024];
    float d0 = rsqrtf((float)(c0 + 1));   // deg = in_degree + 1 (self loop)
    float d1 = rsqrtf((float)(c1 + 1));
    dinv_g[t] = d0;          dinv_g[t + 1024] = d1;
    wsum_g[t] = d0 * d0;     wsum_g[t + 1024] = d1 * d1;   // self-loop term
    ((float4*)y)[t] = make_float4(0.f, 0.f, 0.f, 0.f);     // NB*ND = 4096 floats
    s[t] = c0; s[t + 1024] = c1;
    __syncthreads();
    for (int off = 1; off < 2048; off <<= 1) {
        int v0 = (t >= off) ? s[t - off] : 0;
        int v1 = (t + 1024 >= off) ? s[t + 1024 - off] : 0;
        __syncthreads();
        s[t] += v0;
        s[t + 1024] += v1;
        __syncthreads();
    }
    if (t == 0) offs_g[0] = 0;
    offs_g[t + 1]    = s[t];            // exclusive offsets
    offs_g[t + 1025] = s[t + 1024];
}

// ---- S3: CSR fill + wsum out-edge terms, edge-parallel, global atomics ----
__global__ void k_fill(const int* __restrict__ src, const int* __restrict__ dst,
                       const float* __restrict__ dinv, const int* __restrict__ offs,
                       int* __restrict__ cur, float* __restrict__ wsum,
                       int2* __restrict__ csr) {
    int e = blockIdx.x * 256 + threadIdx.x;
    if (e < NE / 4) {
        int4 s4 = ((const int4*)src)[e];
        int4 d4 = ((const int4*)dst)[e];
        int ss[4] = {s4.x, s4.y, s4.z, s4.w};
        int dd[4] = {d4.x, d4.y, d4.z, d4.w};
        #pragma unroll
        for (int q = 0; q < 4; q++) {
            float w = dinv[ss[q]] * dinv[dd[q]];
            atomicAdd(&wsum[ss[q]], w);
            int p = offs[dd[q]] + atomicAdd(&cur[dd[q]], 1);
            csr[p] = make_int2(ss[q], __float_as_int(w));
        }
    }
}

// ---- fused: gather 32-node tile -> LDS, GEMM vs W1, relu, wsum-weighted reduce ----
// Gather is wave-per-row (float2/lane, 512B coalesced, edge loop wave-uniform).
__global__ __launch_bounds__(256) void k_fused(const float* __restrict__ X,
                                               const int* __restrict__ offs,
                                               const int2* __restrict__ csr,
                                               const float* __restrict__ dinv,
                                               const float* __restrict__ W1,
                                               const float* __restrict__ b1,
                                               const float* __restrict__ wsum,
                                               float* __restrict__ y) {
    __shared__ float4 As4[32 * 33];   // row-major, row stride 33 float4s
    __shared__ float  yred[128];
    const int tid = threadIdx.x;

    // XCD batch-partition swizzle: each XCD's L2 only sees its 4 batches (~4 MB X)
    const int L     = blockIdx.x;
    const int xcd   = L & (NXCD - 1);
    const int slot  = L >> 3;
    const int b     = xcd * BPX + slot / NCHUNK;
    const int chunk = slot % NCHUNK;
    const int n0    = chunk * 32;

    const float2* __restrict__ Xb2 = (const float2*)(X + (size_t)b * NN * ND); // row stride 64
    float2* As2 = (float2*)As4;     // row stride 66 float2s

    if (tid < 128) yred[tid] = 0.f;

    // ---- gather: wave wv owns rows wv*8..wv*8+7; lane ln owns float2 slot ln ----
    const int wv = tid >> 6, ln = tid & 63;
    for (int i = 0; i < 8; i++) {
        const int j = wv * 8 + i;
        const int n = n0 + j;
        float2 a = make_float2(0.f, 0.f);
        if (n < NN) {                       // wave-uniform branch
            float sn = dinv[n]; sn *= sn;
            float2 x = Xb2[n * 64 + ln];
            a.x = sn * x.x; a.y = sn * x.y;
            const int e0 = offs[n], e1 = offs[n + 1];
            #pragma unroll 4
            for (int e = e0; e < e1; e++) {
                int2 ed = csr[e];           // same addr all lanes -> 1 cacheline
                float w = __int_as_float(ed.y);
                float2 xs = Xb2[ed.x * 64 + ln];
                a.x = fmaf(w, xs.x, a.x);
                a.y = fmaf(w, xs.y, a.y);
            }
        }
        As2[j * 66 + ln] = a;
    }
    __syncthreads();

    // ---- GEMM: thread (c=tid&31, rg=tid>>5) -> rows rg*4..+3, cols 4c..4c+3 ----
    const int c = tid & 31, rg = tid >> 5;
    float4 acc[4];
    #pragma unroll
    for (int i = 0; i < 4; i++) acc[i] = make_float4(0.f, 0.f, 0.f, 0.f);
    const float4* __restrict__ W4 = (const float4*)W1 + c;
    #pragma unroll 2
    for (int k4 = 0; k4 < 32; k4++) {
        float4 w0 = W4[(4 * k4 + 0) * 32];
        float4 w1 = W4[(4 * k4 + 1) * 32];
        float4 w2 = W4[(4 * k4 + 2) * 32];
        float4 w3 = W4[(4 * k4 + 3) * 32];
        #pragma unroll
        for (int i = 0; i < 4; i++) {
            float4 a = As4[(rg * 4 + i) * 33 + k4];   // broadcast read
            acc[i].x = fmaf(a.x, w0.x, acc[i].x);
            acc[i].x = fmaf(a.y, w1.x, acc[i].x);
            acc[i].x = fmaf(a.z, w2.x, acc[i].x);
            acc[i].x = fmaf(a.w, w3.x, acc[i].x);
            acc[i].y = fmaf(a.x, w0.y, acc[i].y);
            acc[i].y = fmaf(a.y, w1.y, acc[i].y);
            acc[i].y = fmaf(a.z, w2.y, acc[i].y);
            acc[i].y = fmaf(a.w, w3.y, acc[i].y);
            acc[i].z = fmaf(a.x, w0.z, acc[i].z);
            acc[i].z = fmaf(a.y, w1.z, acc[i].z);
            acc[i].z = fmaf(a.z, w2.z, acc[i].z);
            acc[i].z = fmaf(a.w, w3.z, acc[i].z);
            acc[i].w = fmaf(a.x, w0.w, acc[i].w);
            acc[i].w = fmaf(a.y, w1.w, acc[i].w);
            acc[i].w = fmaf(a.z, w2.w, acc[i].w);
            acc[i].w = fmaf(a.w, w3.w, acc[i].w);
        }
    }

    // ---- epilogue: relu + wsum-weighted reduce over this thread's 4 rows ----
    float4 bias = ((const float4*)b1)[c];
    float4 ya = make_float4(0.f, 0.f, 0.f, 0.f);
    #pragma unroll
    for (int i = 0; i < 4; i++) {
        int n = n0 + rg * 4 + i;
        if (n < NN) {
            float wn = wsum[n];
            ya.x = fmaf(wn, fmaxf(acc[i].x + bias.x, 0.f), ya.x);
            ya.y = fmaf(wn, fmaxf(acc[i].y + bias.y, 0.f), ya.y);
            ya.z = fmaf(wn, fmaxf(acc[i].z + bias.z, 0.f), ya.z);
            ya.w = fmaf(wn, fmaxf(acc[i].w + bias.w, 0.f), ya.w);
        }
    }
    atomicAdd(&yred[4 * c + 0], ya.x);
    atomicAdd(&yred[4 * c + 1], ya.y);
    atomicAdd(&yred[4 * c + 2], ya.z);
    atomicAdd(&yred[4 * c + 3], ya.w);
    __syncthreads();
    if (tid < 128) atomicAdd(&y[b * ND + tid], yred[tid]);
}

// ---- out[b,:] = (1/N) * y[b,:] @ W2 + b2 ----
__global__ __launch_bounds__(128) void k_out(const float* __restrict__ y,
                                             const float* __restrict__ W2,
                                             const float* __restrict__ b2,
                                             float* __restrict__ out) {
    __shared__ float ys[128];
    const int b = blockIdx.x;
    const int d = threadIdx.x;
    ys[d] = y[b * ND + d] * (1.f / (float)NN);
    __syncthreads();
    float acc = b2[d];
    #pragma unroll 8
    for (int k = 0; k < 128; k++)
        acc = fmaf(ys[k], W2[k * ND + d], acc);
    out[b * ND + d] = acc;
}

extern "C" void kernel_launch(void* const* d_in, const int* in_sizes, int n_in,
                              void* d_out, int out_size, void* d_ws, size_t ws_size,
                              hipStream_t stream) {
    (void)in_sizes; (void)n_in; (void)out_size; (void)ws_size;
    const float* X   = (const float*)d_in[0];
    const int*   src = (const int*)d_in[1];
    const int*   dst = (const int*)d_in[2];
    const float* W1  = (const float*)d_in[3];
    const float* b1  = (const float*)d_in[4];
    const float* W2  = (const float*)d_in[5];
    const float* b2  = (const float*)d_in[6];
    float* out = (float*)d_out;

    char* ws = (char*)d_ws;
    int*   cnt  = (int*)  (ws + OFF_CNT);
    int*   cur  = (int*)  (ws + OFF_CUR);
    float* dinv = (float*)(ws + OFF_DINV);
    float* wsum = (float*)(ws + OFF_WSUM);
    int*   offs = (int*)  (ws + OFF_OFFS);
    float* y    = (float*)(ws + OFF_Y);
    int2*  csr  = (int2*) (ws + OFF_CSR);

    hipMemsetAsync(ws, 0, MEMSET_BYTES, stream);                 // cnt + cur
    k_hist<<<(NE / 4 + 255) / 256, 256, 0, stream>>>(dst, cnt);
    k_scan<<<1, 1024, 0, stream>>>(cnt, dinv, wsum, offs, y);
    k_fill<<<(NE / 4 + 255) / 256, 256, 0, stream>>>(src, dst, dinv, offs, cur, wsum, csr);

    k_fused<<<NXCD * BPX * NCHUNK, 256, 0, stream>>>(X, offs, csr, dinv, W1, b1, wsum, y);
    k_out<<<NB, 128, 0, stream>>>(y, W2, b2, out);
}